// Round 1
// baseline (13236.562 us; speedup 1.0000x reference)
//
#include <hip/hip_runtime.h>

#define NODES 100000
#define NEDGE 1600000
#define NREL  3
#define DIN   128
#define DHID  128
#define DOUT  64

// ---------------------------------------------------------------------------
// degree histogram: deg layout = [2][NREL][NODES] uints: first NREL*NODES is
// out-degree (by src), second is in-degree (by dst)
__global__ void deg_kernel(const int* __restrict__ edges, unsigned* __restrict__ deg) {
    const int r = blockIdx.y;
    const int* __restrict__ src = edges + (long)r * 2 * NEDGE;
    const int* __restrict__ dst = src + NEDGE;
    for (int e = blockIdx.x * blockDim.x + threadIdx.x; e < NEDGE;
         e += gridDim.x * blockDim.x) {
        atomicAdd(&deg[r * NODES + src[e]], 1u);
        atomicAdd(&deg[NREL * NODES + r * NODES + dst[e]], 1u);
    }
}

// in-place uint degree -> float rsqrt(max(deg,1))
__global__ void rsq_kernel(float* __restrict__ buf) {
    const int total = 2 * NREL * NODES;
    int i = blockIdx.x * blockDim.x + threadIdx.x;
    if (i < total) {
        unsigned d = ((const unsigned*)buf)[i];
        buf[i] = rsqrtf((float)(d ? d : 1u));
    }
}

// ---------------------------------------------------------------------------
// m[row, c] = sum_k x[row,k]*rsq[row] * W[k,c]     (W row-major [DIN][ODIM])
// block = 256 threads, 16 rows per block. W transposed into LDS [ODIM][132].
template <int ODIM>
__global__ __launch_bounds__(256) void gemm_scaled(
    const float* __restrict__ x, const float* __restrict__ rsq,
    const float* __restrict__ W, float* __restrict__ m) {
    extern __shared__ float lds[];
    float* Wt = lds;                  // [ODIM][132]  (pad to tame bank conflicts)
    float* Xs = lds + ODIM * 132;     // [16][DIN]
    const int tid = threadIdx.x;

    for (int idx = tid; idx < DIN * ODIM; idx += 256) {
        int k = idx / ODIM, c = idx % ODIM;
        Wt[c * 132 + k] = W[idx];
    }
    const int row0 = blockIdx.x * 16;
    for (int idx = tid; idx < 16 * DIN; idx += 256) {
        int rr = idx / DIN, k = idx % DIN;
        int row = row0 + rr;
        Xs[idx] = x[(long)row * DIN + k] * rsq[row];
    }
    __syncthreads();

    constexpr int G = 256 / ODIM;   // 2 (ODIM=128) or 4 (ODIM=64)
    constexpr int RPT = 16 / G;     // 8 or 4 rows per thread
    const int c = tid % ODIM;
    const int rg = tid / ODIM;
    float acc[RPT];
#pragma unroll
    for (int j = 0; j < RPT; j++) acc[j] = 0.f;

    for (int k = 0; k < DIN; k += 4) {
        const float4 wv = *(const float4*)&Wt[c * 132 + k];
#pragma unroll
        for (int j = 0; j < RPT; j++) {
            const float4 xv = *(const float4*)&Xs[(rg + j * G) * DIN + k];
            acc[j] += xv.x * wv.x + xv.y * wv.y + xv.z * wv.z + xv.w * wv.w;
        }
    }
#pragma unroll
    for (int j = 0; j < RPT; j++) {
        int row = row0 + rg + j * G;
        m[(long)row * ODIM + c] = acc[j];
    }
}

// ---------------------------------------------------------------------------
// acc[dst] += m[src] * rsq_in[dst]   (per-edge, folded deg_in scaling lets all
// relations share one accumulator)
template <int DIMS>
__global__ __launch_bounds__(256) void scatter_kernel(
    const float* __restrict__ m, const int* __restrict__ src,
    const int* __restrict__ dst, const float* __restrict__ rin,
    float* __restrict__ acc) {
    constexpr int D4 = DIMS / 4;            // 32 or 16 (power of 2)
    const long total = (long)NEDGE * D4;
    const long stride = (long)gridDim.x * blockDim.x;
    for (long idx = (long)blockIdx.x * blockDim.x + threadIdx.x; idx < total;
         idx += stride) {
        const int e = (int)(idx / D4);
        const int g = (int)(idx % D4);
        const int s = src[e];
        const int d = dst[e];
        const float sc = rin[d];
        const float4 v = *(const float4*)(m + (long)s * DIMS + g * 4);
        float* a = acc + (long)d * DIMS + g * 4;
        unsafeAtomicAdd(a + 0, v.x * sc);
        unsafeAtomicAdd(a + 1, v.y * sc);
        unsafeAtomicAdd(a + 2, v.z * sc);
        unsafeAtomicAdd(a + 3, v.w * sc);
    }
}

// h = relu(acc + sum_r b1[r])
__global__ void finalize1(float* __restrict__ h, const float* __restrict__ b1) {
    long i = (long)blockIdx.x * blockDim.x + threadIdx.x;
    if (i < (long)NODES * DHID) {
        int c = (int)(i & (DHID - 1));
        float bias = b1[c] + b1[DHID + c] + b1[2 * DHID + c];
        float v = h[i] + bias;
        h[i] = v > 0.f ? v : 0.f;
    }
}

// out += sum_r b2[r]
__global__ void finalize2(float* __restrict__ out, const float* __restrict__ b2) {
    long i = (long)blockIdx.x * blockDim.x + threadIdx.x;
    if (i < (long)NODES * DOUT) {
        int c = (int)(i & (DOUT - 1));
        out[i] += b2[c] + b2[DOUT + c] + b2[2 * DOUT + c];
    }
}

// ---------------------------------------------------------------------------
extern "C" void kernel_launch(void* const* d_in, const int* in_sizes, int n_in,
                              void* d_out, int out_size, void* d_ws, size_t ws_size,
                              hipStream_t stream) {
    const float* x  = (const float*)d_in[0];
    const int* edges = (const int*)d_in[1];
    const float* W1 = (const float*)d_in[2];
    const float* b1 = (const float*)d_in[3];
    const float* W2 = (const float*)d_in[4];
    const float* b2 = (const float*)d_in[5];
    float* out = (float*)d_out;

    char* ws = (char*)d_ws;
    float* rsq = (float*)ws;  // [2][NREL][NODES]: out-norms then in-norms
    size_t off = (((size_t)2 * NREL * NODES * 4) + 255) & ~(size_t)255;
    float* m = (float*)(ws + off);           // [NODES][DHID] message buffer
    off += (size_t)NODES * DHID * 4;
    float* acc1 = (float*)(ws + off);        // [NODES][DHID] layer-1 accumulator / h
    // total ws use: ~105 MB

    // --- degrees + norms (shared by both layers) ---
    hipMemsetAsync(rsq, 0, (size_t)2 * NREL * NODES * 4, stream);
    deg_kernel<<<dim3(1024, NREL), 256, 0, stream>>>(edges, (unsigned*)rsq);
    rsq_kernel<<<(2 * NREL * NODES + 255) / 256, 256, 0, stream>>>(rsq);

    // --- layer 1 ---
    hipMemsetAsync(acc1, 0, (size_t)NODES * DHID * 4, stream);
    for (int r = 0; r < NREL; r++) {
        const int* src = edges + (long)r * 2 * NEDGE;
        const int* dst = src + NEDGE;
        gemm_scaled<DHID><<<NODES / 16, 256, (DHID * 132 + 16 * DIN) * 4, stream>>>(
            x, rsq + (size_t)r * NODES, W1 + (size_t)r * DIN * DHID, m);
        scatter_kernel<DHID><<<2048, 256, 0, stream>>>(
            m, src, dst, rsq + (size_t)(NREL + r) * NODES, acc1);
    }
    finalize1<<<(NODES * DHID + 255) / 256, 256, 0, stream>>>(acc1, b1);

    // --- layer 2 ---
    hipMemsetAsync(out, 0, (size_t)NODES * DOUT * 4, stream);
    for (int r = 0; r < NREL; r++) {
        const int* src = edges + (long)r * 2 * NEDGE;
        const int* dst = src + NEDGE;
        gemm_scaled<DOUT><<<NODES / 16, 256, (DOUT * 132 + 16 * DIN) * 4, stream>>>(
            acc1, rsq + (size_t)r * NODES, W2 + (size_t)r * DHID * DOUT, m);
        scatter_kernel<DOUT><<<2048, 256, 0, stream>>>(
            m, src, dst, rsq + (size_t)(NREL + r) * NODES, out);
    }
    finalize2<<<(NODES * DOUT + 255) / 256, 256, 0, stream>>>(out, b2);
}

// Round 2
// 2542.917 us; speedup vs baseline: 5.2053x; 5.2053x over previous
//
#include <hip/hip_runtime.h>

#define NODES 100000
#define NEDGE 1600000
#define NREL  3
#define DIN   128
#define DHID  128
#define DOUT  64

// ---------------------------------------------------------------------------
// degree histogram: deg layout = [2][NREL][NODES] uints: first NREL*NODES is
// out-degree (by src), second is in-degree (by dst)
__global__ void deg_kernel(const int* __restrict__ edges, unsigned* __restrict__ deg) {
    const int r = blockIdx.y;
    const int* __restrict__ src = edges + (long)r * 2 * NEDGE;
    const int* __restrict__ dst = src + NEDGE;
    for (int e = blockIdx.x * blockDim.x + threadIdx.x; e < NEDGE;
         e += gridDim.x * blockDim.x) {
        atomicAdd(&deg[r * NODES + src[e]], 1u);
        atomicAdd(&deg[NREL * NODES + r * NODES + dst[e]], 1u);
    }
}

// in-place uint degree -> float rsqrt(max(deg,1))
__global__ void rsq_kernel(float* __restrict__ buf) {
    const int total = 2 * NREL * NODES;
    int i = blockIdx.x * blockDim.x + threadIdx.x;
    if (i < total) {
        unsigned d = ((const unsigned*)buf)[i];
        buf[i] = rsqrtf((float)(d ? d : 1u));
    }
}

// ---------------------------------------------------------------------------
// exclusive scan of in-degree -> rowptr (and cursor copy). One block/relation.
__global__ __launch_bounds__(256) void scan_kernel(
    const unsigned* __restrict__ deg_in, int* __restrict__ rowptr,
    int* __restrict__ cursor) {
    const int r = blockIdx.x;
    const unsigned* __restrict__ d = deg_in + (size_t)r * NODES;
    int* __restrict__ rp = rowptr + (size_t)r * (NODES + 1);
    int* __restrict__ cur = cursor + (size_t)r * NODES;
    const int tid = threadIdx.x;
    const int lane = tid & 63, wid = tid >> 6;
    __shared__ int wsum[4];
    __shared__ int carry, tile_total;
    if (tid == 0) carry = 0;
    __syncthreads();

    for (int base = 0; base < NODES; base += 256) {
        int i = base + tid;
        int v = (i < NODES) ? (int)d[i] : 0;
        // wave inclusive scan
        int incl = v;
        for (int off = 1; off < 64; off <<= 1) {
            int t = __shfl_up(incl, off, 64);
            if (lane >= off) incl += t;
        }
        if (lane == 63) wsum[wid] = incl;
        __syncthreads();
        if (tid == 0) {
            int a = 0;
            for (int w = 0; w < 4; w++) { int t = wsum[w]; wsum[w] = a; a += t; }
            tile_total = a;
        }
        __syncthreads();
        if (i < NODES) {
            int excl = carry + wsum[wid] + (incl - v);
            rp[i] = excl;
            cur[i] = excl;
        }
        __syncthreads();
        if (tid == 0) carry += tile_total;
        __syncthreads();
    }
    if (tid == 0) rp[NODES] = carry;
}

// scatter edge src ids into CSR slots via atomic cursor
__global__ void fill_kernel(const int* __restrict__ edges, int* __restrict__ cursor,
                            int* __restrict__ csr_src) {
    const int r = blockIdx.y;
    const int* __restrict__ src = edges + (long)r * 2 * NEDGE;
    const int* __restrict__ dst = src + NEDGE;
    int* __restrict__ cur = cursor + (size_t)r * NODES;
    int* __restrict__ cs = csr_src + (size_t)r * NEDGE;
    for (int e = blockIdx.x * blockDim.x + threadIdx.x; e < NEDGE;
         e += gridDim.x * blockDim.x) {
        int pos = atomicAdd(&cur[dst[e]], 1);
        cs[pos] = src[e];
    }
}

// ---------------------------------------------------------------------------
// m[row, c] = sum_k x[row,k]*rsq[row] * W[k,c]     (W row-major [DIN][ODIM])
template <int ODIM>
__global__ __launch_bounds__(256) void gemm_scaled(
    const float* __restrict__ x, const float* __restrict__ rsq,
    const float* __restrict__ W, float* __restrict__ m) {
    extern __shared__ float lds[];
    float* Wt = lds;                  // [ODIM][132]
    float* Xs = lds + ODIM * 132;     // [16][DIN]
    const int tid = threadIdx.x;

    for (int idx = tid; idx < DIN * ODIM; idx += 256) {
        int k = idx / ODIM, c = idx % ODIM;
        Wt[c * 132 + k] = W[idx];
    }
    const int row0 = blockIdx.x * 16;
    for (int idx = tid; idx < 16 * DIN; idx += 256) {
        int rr = idx / DIN, k = idx % DIN;
        int row = row0 + rr;
        Xs[idx] = x[(long)row * DIN + k] * rsq[row];
    }
    __syncthreads();

    constexpr int G = 256 / ODIM;
    constexpr int RPT = 16 / G;
    const int c = tid % ODIM;
    const int rg = tid / ODIM;
    float acc[RPT];
#pragma unroll
    for (int j = 0; j < RPT; j++) acc[j] = 0.f;

    for (int k = 0; k < DIN; k += 4) {
        const float4 wv = *(const float4*)&Wt[c * 132 + k];
#pragma unroll
        for (int j = 0; j < RPT; j++) {
            const float4 xv = *(const float4*)&Xs[(rg + j * G) * DIN + k];
            acc[j] += xv.x * wv.x + xv.y * wv.y + xv.z * wv.z + xv.w * wv.w;
        }
    }
#pragma unroll
    for (int j = 0; j < RPT; j++) {
        int row = row0 + rg + j * G;
        m[(long)row * ODIM + c] = acc[j];
    }
}

// ---------------------------------------------------------------------------
// pull aggregation: acc[v] = beta*acc[v] + rin[v] * sum_{e in csr(v)} m[src_e]
template <int ODIM>
__global__ __launch_bounds__(256) void agg_kernel(
    const float* __restrict__ m, const int* __restrict__ rowptr,
    const int* __restrict__ csr_src, const float* __restrict__ rin,
    float* __restrict__ acc, float beta) {
    constexpr int NPB = 256 / ODIM;          // 2 (128) or 4 (64)
    const int v = blockIdx.x * NPB + threadIdx.x / ODIM;
    const int col = threadIdx.x % ODIM;
    if (v >= NODES) return;
    const int b = rowptr[v], e = rowptr[v + 1];
    float sum = 0.f;
    int i = b;
    for (; i + 1 < e; i += 2) {
        int s0 = csr_src[i], s1 = csr_src[i + 1];
        float v0 = m[(size_t)s0 * ODIM + col];
        float v1 = m[(size_t)s1 * ODIM + col];
        sum += v0;
        sum += v1;
    }
    if (i < e) sum += m[(size_t)csr_src[i] * ODIM + col];
    const size_t o = (size_t)v * ODIM + col;
    const float res = sum * rin[v];
    acc[o] = (beta == 0.f) ? res : acc[o] + res;
}

// h = relu(acc + sum_r b1[r])
__global__ void finalize1(float* __restrict__ h, const float* __restrict__ b1) {
    long i = (long)blockIdx.x * blockDim.x + threadIdx.x;
    if (i < (long)NODES * DHID) {
        int c = (int)(i & (DHID - 1));
        float bias = b1[c] + b1[DHID + c] + b1[2 * DHID + c];
        float v = h[i] + bias;
        h[i] = v > 0.f ? v : 0.f;
    }
}

// out += sum_r b2[r]
__global__ void finalize2(float* __restrict__ out, const float* __restrict__ b2) {
    long i = (long)blockIdx.x * blockDim.x + threadIdx.x;
    if (i < (long)NODES * DOUT) {
        int c = (int)(i & (DOUT - 1));
        out[i] += b2[c] + b2[DOUT + c] + b2[2 * DOUT + c];
    }
}

// ---------------------------------------------------------------------------
extern "C" void kernel_launch(void* const* d_in, const int* in_sizes, int n_in,
                              void* d_out, int out_size, void* d_ws, size_t ws_size,
                              hipStream_t stream) {
    const float* x  = (const float*)d_in[0];
    const int* edges = (const int*)d_in[1];
    const float* W1 = (const float*)d_in[2];
    const float* b1 = (const float*)d_in[3];
    const float* W2 = (const float*)d_in[4];
    const float* b2 = (const float*)d_in[5];
    float* out = (float*)d_out;

    char* ws = (char*)d_ws;
    size_t off = 0;
    auto alloc = [&](size_t bytes) {
        void* p = ws + off;
        off = (off + bytes + 255) & ~(size_t)255;
        return p;
    };
    float* rsq     = (float*)alloc((size_t)2 * NREL * NODES * 4);   // 2.4 MB
    int*   rowptr  = (int*)alloc((size_t)NREL * (NODES + 1) * 4);   // 1.2 MB
    int*   cursor  = (int*)alloc((size_t)NREL * NODES * 4);         // 1.2 MB
    int*   csr_src = (int*)alloc((size_t)NREL * NEDGE * 4);         // 19.2 MB
    float* m       = (float*)alloc((size_t)NODES * DHID * 4);       // 51.2 MB
    float* acc1    = (float*)alloc((size_t)NODES * DHID * 4);       // 51.2 MB
    // total ~126.5 MB

    // --- degrees + norms + CSR build (shared by both layers) ---
    hipMemsetAsync(rsq, 0, (size_t)2 * NREL * NODES * 4, stream);
    deg_kernel<<<dim3(1024, NREL), 256, 0, stream>>>(edges, (unsigned*)rsq);
    scan_kernel<<<NREL, 256, 0, stream>>>(
        (const unsigned*)rsq + (size_t)NREL * NODES, rowptr, cursor);
    rsq_kernel<<<(2 * NREL * NODES + 255) / 256, 256, 0, stream>>>(rsq);
    fill_kernel<<<dim3(1024, NREL), 256, 0, stream>>>(edges, cursor, csr_src);

    // --- layer 1 ---
    for (int r = 0; r < NREL; r++) {
        gemm_scaled<DHID><<<NODES / 16, 256, (DHID * 132 + 16 * DIN) * 4, stream>>>(
            x, rsq + (size_t)r * NODES, W1 + (size_t)r * DIN * DHID, m);
        agg_kernel<DHID><<<NODES / 2, 256, 0, stream>>>(
            m, rowptr + (size_t)r * (NODES + 1), csr_src + (size_t)r * NEDGE,
            rsq + (size_t)(NREL + r) * NODES, acc1, r == 0 ? 0.f : 1.f);
    }
    finalize1<<<(NODES * DHID + 255) / 256, 256, 0, stream>>>(acc1, b1);

    // --- layer 2 ---
    for (int r = 0; r < NREL; r++) {
        gemm_scaled<DOUT><<<NODES / 16, 256, (DOUT * 132 + 16 * DIN) * 4, stream>>>(
            acc1, rsq + (size_t)r * NODES, W2 + (size_t)r * DHID * DOUT, m);
        agg_kernel<DOUT><<<NODES / 4, 256, 0, stream>>>(
            m, rowptr + (size_t)r * (NODES + 1), csr_src + (size_t)r * NEDGE,
            rsq + (size_t)(NREL + r) * NODES, out, r == 0 ? 0.f : 1.f);
    }
    finalize2<<<(NODES * DOUT + 255) / 256, 256, 0, stream>>>(out, b2);
}